// Round 6
// baseline (227.426 us; speedup 1.0000x reference)
//
#include <hip/hip_runtime.h>
#include <math.h>

#define S 128
#define KA 25
#define PATCH 625
#define FEAT 1250
#define PI_F 3.14159265358979323846f
#define PADW 152             // 128 + 24; ALSO the x row stride (152x152 input)
#define PADA (PADW * PADW)   // 23104

// Env tables residue-split: slot(r) = (r&3)*160 + (r>>2); in the f4 loops all
// lanes of a j-step share (r&3) -> stride-1 conflict-free LDS reads.
//
// d_ws layout (floats):
//   [0, 640)             LRI env (residue-split, normalized)
//   [640, 1280)          AFF env (residue-split)
//   [1280, 24384)        padded lat0, 152x152, border 0
//   [24384, 47488)       padded latf, 152x152, border HOMEO_TARGET
//   [47488, 51584)       per-block corr partials (4096)
#define WS_LRI 0
#define WS_AE 640
#define WS_LAT0P 1280
#define WS_LATFP 24384
#define WS_PART 47488
#define NPART 4096

// floor(r/25) for r in [0,625): exact (25*10486 = 2^18+6).
__device__ __forceinline__ int div25(int r) { return (r * 10486) >> 18; }
// window offset for patch index r: ki*152 + kj = r + 127*(r/25)
__device__ __forceinline__ int woff(int r) { return r + 127 * div25(r); }
__device__ __forceinline__ int eslot(int r) { return (r & 3) * 160 + (r >> 2); }

// Async global->LDS, 16B per lane per instr.  LDS dest is WAVE-UNIFORM base
// (HW adds lane*16); global src is per-lane.  Data lands in LDS, not VGPRs,
// so the compiler CANNOT re-sink these into load-use pairs (which is what
// killed round 5's register prefetch: VGPR stayed 28, MLP stayed ~1).
__device__ __forceinline__ void gld16(const float* g, float* l) {
    __builtin_amdgcn_global_load_lds(
        (const __attribute__((address_space(1))) void*)g,
        (__attribute__((address_space(3))) void*)l, 16, 0, 0);
}

// ---------------------------------------------------------------------------
// Kernel 0 (16 blocks): block 0 builds env tables (bit-identical values to
// the original); all blocks fill the padded lat0 (0) / latf (0.04) arrays.
// ---------------------------------------------------------------------------
__global__ __launch_bounds__(256) void k_init(float* __restrict__ ws) {
    const int tid = threadIdx.x;
    if (blockIdx.x == 0) {
        __shared__ float s_tmp[640];
        __shared__ float s_red[4];
        for (int s = tid; s < 640; s += 256) {     // AFF env
            int q = s / 160, t = s - q * 160;
            int r = (t << 2) | q;
            float v = 0.0f;
            if (r < PATCH) {
                float di = (float)div25(r) - 12.0f;
                float dj = (float)(r - 25 * div25(r)) - 12.0f;
                float d = sqrtf(di * di + dj * dj);
                if (d < 12.5f) {
                    float c = cosf(d * (PI_F / 25.0f));
                    v = c * c;
                }
            }
            ws[WS_AE + s] = v;
        }
        float m = 0.0f;
        for (int s = tid; s < 640; s += 256) {     // LRI env
            int q = s / 160, t = s - q * 160;
            int r = (t << 2) | q;
            float v = 0.0f;
            if (r < PATCH) {
                float di = (float)div25(r) - 12.0f;
                float dj = (float)(r - 25 * div25(r)) - 12.0f;
                float d = sqrtf(di * di + dj * dj);
                if (d < 12.5f) {
                    float c1 = cosf(d * (PI_F / 25.0f));
                    float inh = 0.0f;
                    if (d < 4.5f) {
                        float c2 = cosf(d * (PI_F / 9.0f));
                        inh = c2 * c2;
                    }
                    v = c1 * c1 * (1.0f - inh);
                }
            }
            s_tmp[s] = v;
            m = fmaxf(m, v);
        }
        for (int o = 32; o; o >>= 1) m = fmaxf(m, __shfl_down(m, o));
        if (!(tid & 63)) s_red[tid >> 6] = m;
        __syncthreads();
        float inv = 1.0f / fmaxf(fmaxf(s_red[0], s_red[1]),
                                 fmaxf(s_red[2], s_red[3]));
        for (int s = tid; s < 640; s += 256) ws[WS_LRI + s] = s_tmp[s] * inv;
    }
    const int gid = blockIdx.x * 256 + tid;
    const int gsz = gridDim.x * 256;
    for (int i = gid; i < 2 * PADA; i += gsz) {
        if (i < PADA) ws[WS_LAT0P + i] = 0.0f;
        else          ws[WS_LATFP + i - PADA] = 0.04f;
    }
}

// ---------------------------------------------------------------------------
// Kernel 1: FUSED tiles + raw_aff + padded lat0.  One wave per row l (4096
// blocks x 4 waves).  rfs row is staged to LDS with 5 back-to-back
// global_load_lds_dwordx4 (structural MLP=5/wave, ~24 waves/CU resident ->
// ~120 KB in flight per CU), then consumed via ds_read_b128.  Head/tail
// (unaligned 2 elems) go direct from global.  Accumulation order unchanged
// vs round 5 -> bit-identical outputs.
// ---------------------------------------------------------------------------
__global__ __launch_bounds__(256) void k_afftiles(const float* __restrict__ x,
                                                  const float* __restrict__ rfs,
                                                  const float* __restrict__ ada,
                                                  float* __restrict__ raw_aff,
                                                  float* __restrict__ tiles,
                                                  float* __restrict__ ws) {
    __shared__ float s_ae[640];
    __shared__ float s_st[4 * 1280];               // 5120 B per wave
    const int tid = threadIdx.x;
    for (int i = tid; i < 640; i += 256) s_ae[i] = ws[WS_AE + i];
    __syncthreads();

    const int lane = tid & 63;
    const int wv = tid >> 6;
    const int l = blockIdx.x * 4 + wv;             // 16384 waves, 1 row each
    const int li = l >> 7, lj = l & 127;
    const int wb = li * PADW + lj;                 // x row stride is also 152
    const long B = (long)l * FEAT;
    const int peel = (l & 1) ? 2 : 0;              // (1250*l)*4B mod 16 = 8(l&1)

    // ---- issue the whole-row stage FIRST (5 async 1KB loads in flight) ----
    const float* gp = rfs + B + peel + 4 * lane;   // per-lane global src
    float* lp = s_st + wv * 1280;                  // wave-uniform LDS base
#pragma unroll
    for (int i = 0; i < 4; ++i) gld16(gp + 256 * i, lp + 256 * i);
    if (lane < 56) gld16(gp + 1024, lp + 1024);    // 312 f4 = 4*64 + 56

    float acc = 0.0f;
    if (lane < peel) {                              // l odd: f=0,1 (c=0, woff=f)
        int f = lane;
        float t = x[wb + f] * s_ae[eslot(f)];
        tiles[B + f] = t;
        acc += t * fmaxf(rfs[B + f], 0.0f);
    }
    if (lane < 2 - peel) {                          // l even: f=1248,1249 (c=1)
        int f = 1248 + lane;
        int r = f - PATCH;
        float t = x[PADA + wb + woff(r)] * s_ae[eslot(r)];
        tiles[B + f] = t;
        acc += t * fmaxf(rfs[B + f], 0.0f);
    }

    asm volatile("s_waitcnt vmcnt(0)" ::: "memory");
    __builtin_amdgcn_sched_barrier(0);             // rule 18: pin the wait

    auto consume = [&](int i) {
        const int k = i * 64 + lane;
        const float4 rv = *reinterpret_cast<const float4*>(lp + 4 * k);
        const int f0 = peel + 4 * k;
#pragma unroll
        for (int j = 0; j < 4; ++j) {
            int f = f0 + j;
            int c = (f >= PATCH) ? 1 : 0;
            int r = f - c * PATCH;
            float t = x[c * PADA + wb + woff(r)] * s_ae[eslot(r)];
            tiles[B + f] = t;
            acc += t * fmaxf((&rv.x)[j], 0.0f);
        }
    };
    consume(0); consume(1); consume(2); consume(3);
    if (lane < 56) consume(4);

    for (int o = 32; o; o >>= 1) acc += __shfl_down(acc, o);
    if (!lane) {
        raw_aff[l] = acc;
        ws[WS_LAT0P + (li + 12) * PADW + (lj + 12)] = fmaxf(acc - ada[l], 0.0f);
    }
}

// ---------------------------------------------------------------------------
// Kernel 2: final lat.  One wave per row.  lw row staged to LDS with 3
// global_load_lds_dwordx4 (2 full + 1 lanes<rem); head/tail direct.
// lat0 gathered from the padded ws array (90 KB, L2-hot).
// ---------------------------------------------------------------------------
__global__ __launch_bounds__(256) void k_lat(const float* __restrict__ raw_aff,
                                             const float* __restrict__ ada,
                                             const float* __restrict__ lw,
                                             float* __restrict__ latf,
                                             float* __restrict__ ws) {
    __shared__ float s_le[640];
    __shared__ float s_st[4 * 640];                // 2560 B per wave
    const int tid = threadIdx.x;
    for (int i = tid; i < 640; i += 256) s_le[i] = ws[WS_LRI + i];
    __syncthreads();

    const int lane = tid & 63;
    const int wv = tid >> 6;
    const int l = blockIdx.x * 4 + wv;
    const int li = l >> 7, lj = l & 127;
    const int wb = li * PADW + lj;
    const long B = (long)l * PATCH;
    const int peel = (4 - (l & 3)) & 3;            // (625*l)*4B mod 16 = 4(l&3)
    const int n4 = (PATCH - peel) >> 2;            // 155 or 156
    const int rem = n4 - 128;                      // 27 or 28
    const int tail = (PATCH - peel) & 3;
    const float* __restrict__ plat0 = ws + WS_LAT0P;

    const float* gp = lw + B + peel + 4 * lane;
    float* lp = s_st + wv * 640;
    gld16(gp, lp);
    gld16(gp + 256, lp + 256);
    if (lane < rem) gld16(gp + 512, lp + 512);

    float acc = 0.0f;
    if (lane < peel) {                              // f<3: woff(f)=f
        int f = lane;
        acc += plat0[wb + f] * s_le[eslot(f)] * fmaxf(lw[B + f], 0.0f);
    }
    if (lane < tail) {
        int f = peel + 4 * n4 + lane;
        acc += plat0[wb + woff(f)] * s_le[eslot(f)] * fmaxf(lw[B + f], 0.0f);
    }

    asm volatile("s_waitcnt vmcnt(0)" ::: "memory");
    __builtin_amdgcn_sched_barrier(0);

    auto consume = [&](int i) {
        const int k = i * 64 + lane;
        const float4 w4 = *reinterpret_cast<const float4*>(lp + 4 * k);
        const int f0 = peel + 4 * k;
#pragma unroll
        for (int j = 0; j < 4; ++j) {
            int f = f0 + j;
            acc += plat0[wb + woff(f)] * s_le[eslot(f)] * fmaxf((&w4.x)[j], 0.0f);
        }
    };
    consume(0); consume(1);
    if (lane < rem) consume(2);

    for (int o = 32; o; o >>= 1) acc += __shfl_down(acc, o);
    if (!lane) {
        float aff_l = raw_aff[l] - ada[l];
        float lat0_l = fmaxf(aff_l, 0.0f);
        float v = (lat0_l - acc) /* *STRENGTH=1 */ + aff_l;
        float lv = tanhf(fmaxf(v, 0.0f));
        latf[l] = lv;
        ws[WS_LATFP + (li + 12) * PADW + (lj + 12)] = lv;
    }
}

// ---------------------------------------------------------------------------
// Kernel 3: corr partials.  Same staged structure on padded latf (border
// 0.04 = HOMEO_TARGET from k_init).
// ---------------------------------------------------------------------------
__global__ __launch_bounds__(256) void k_corr(const float* __restrict__ latf,
                                              const float* __restrict__ lw,
                                              float* __restrict__ ws) {
    __shared__ float s_le[640];
    __shared__ float s_st[4 * 640];
    __shared__ float s_red[4];
    const int tid = threadIdx.x;
    for (int i = tid; i < 640; i += 256) s_le[i] = ws[WS_LRI + i];
    __syncthreads();

    const int lane = tid & 63, wv = tid >> 6;
    const int l = blockIdx.x * 4 + wv;
    const int li = l >> 7, lj = l & 127;
    const int wb = li * PADW + lj;
    const long B = (long)l * PATCH;
    const int peel = (4 - (l & 3)) & 3;
    const int n4 = (PATCH - peel) >> 2;
    const int rem = n4 - 128;
    const int tail = (PATCH - peel) & 3;
    const float* __restrict__ platf = ws + WS_LATFP;

    const float* gp = lw + B + peel + 4 * lane;
    float* lp = s_st + wv * 640;
    gld16(gp, lp);
    gld16(gp + 256, lp + 256);
    if (lane < rem) gld16(gp + 512, lp + 512);

    float acc = 0.0f;
    if (lane < peel) {
        int f = lane;
        acc += platf[wb + f] * s_le[eslot(f)] * fmaxf(lw[B + f], 0.0f);
    }
    if (lane < tail) {
        int f = peel + 4 * n4 + lane;
        acc += platf[wb + woff(f)] * s_le[eslot(f)] * fmaxf(lw[B + f], 0.0f);
    }

    asm volatile("s_waitcnt vmcnt(0)" ::: "memory");
    __builtin_amdgcn_sched_barrier(0);

    auto consume = [&](int i) {
        const int k = i * 64 + lane;
        const float4 w4 = *reinterpret_cast<const float4*>(lp + 4 * k);
        const int f0 = peel + 4 * k;
#pragma unroll
        for (int j = 0; j < 4; ++j) {
            int f = f0 + j;
            acc += platf[wb + woff(f)] * s_le[eslot(f)] * fmaxf((&w4.x)[j], 0.0f);
        }
    };
    consume(0); consume(1);
    if (lane < rem) consume(2);

    for (int o = 32; o; o >>= 1) acc += __shfl_down(acc, o);

    if (!lane) s_red[wv] = acc * latf[l];
    __syncthreads();
    if (!tid)
        ws[WS_PART + blockIdx.x] = s_red[0] + s_red[1] + s_red[2] + s_red[3];
}

// ---------------------------------------------------------------------------
// Kernel 4: deterministic sum of 4096 partials -> corr scalar.
// ---------------------------------------------------------------------------
__global__ __launch_bounds__(256) void k_reduce(const float* __restrict__ ws,
                                                float* __restrict__ corr) {
    __shared__ float s_red[4];
    const int tid = threadIdx.x;
    const int lane = tid & 63, wv = tid >> 6;
    float acc = 0.0f;
    for (int i = tid; i < NPART; i += 256) acc += ws[WS_PART + i];
    for (int o = 32; o; o >>= 1) acc += __shfl_down(acc, o);
    if (!lane) s_red[wv] = acc;
    __syncthreads();
    if (!tid) corr[0] = s_red[0] + s_red[1] + s_red[2] + s_red[3];
}

// ---------------------------------------------------------------------------
// d_out layout (flat, return order):
//   [0, 16384)              raw_aff   [1,1,128,128]
//   [16384, 32768)          lat       [1,1,128,128]
//   [32768]                 lat_correlations (scalar)
//   [32769, 32769+20480000) tiles     [16384, 1, 1250]
// ---------------------------------------------------------------------------
extern "C" void kernel_launch(void* const* d_in, const int* in_sizes, int n_in,
                              void* d_out, int out_size, void* d_ws, size_t ws_size,
                              hipStream_t stream) {
    const float* x   = (const float*)d_in[0];   // [1,2,152,152]
    const float* rfs = (const float*)d_in[1];   // [16384,1250,1]
    const float* lw  = (const float*)d_in[2];   // [16384,625,1]
    const float* ada = (const float*)d_in[3];   // [1,1,128,128]

    float* out      = (float*)d_out;
    float* raw_aff  = out;
    float* latf     = out + S * S;
    float* corr     = out + 2 * S * S;
    float* tiles    = out + 2 * S * S + 1;
    float* ws       = (float*)d_ws;

    k_init<<<16, 256, 0, stream>>>(ws);
    k_afftiles<<<4096, 256, 0, stream>>>(x, rfs, ada, raw_aff, tiles, ws);
    k_lat<<<4096, 256, 0, stream>>>(raw_aff, ada, lw, latf, ws);
    k_corr<<<4096, 256, 0, stream>>>(latf, lw, ws);
    k_reduce<<<1, 256, 0, stream>>>(ws, corr);
}

// Round 7
// 225.345 us; speedup vs baseline: 1.0092x; 1.0092x over previous
//
#include <hip/hip_runtime.h>
#include <math.h>

#define S 128
#define KA 25
#define PATCH 625
#define FEAT 1250
#define PI_F 3.14159265358979323846f
#define PADW 152             // 128 + 24; ALSO the x row stride (152x152 input)
#define PADA (PADW * PADW)   // 23104

// d_ws layout (floats) -- env tables are LINEAR now (f-dense consume):
//   [0, 625)             LRI env (normalized)
//   [640, 1265)          AFF env
//   [1280, 24384)        padded lat0, 152x152, border 0
//   [24384, 47488)       padded latf, 152x152, border HOMEO_TARGET
//   [47488, 48512)       per-block corr partials (1024)
#define WS_LRI 0
#define WS_AE 640
#define WS_LAT0P 1280
#define WS_LATFP 24384
#define WS_PART 47488
#define NPART 1024

// floor(r/25) for r in [0,625): exact (25*10486 = 2^18+6).
__device__ __forceinline__ int div25(int r) { return (r * 10486) >> 18; }

// Async global->LDS, 16B/lane.  LDS dest must be wave-uniform (HW adds
// lane*16); global src is per-lane.
__device__ __forceinline__ void gld16(const float* g, float* l) {
    __builtin_amdgcn_global_load_lds(
        (const __attribute__((address_space(1))) void*)g,
        (__attribute__((address_space(3))) void*)l, 16, 0, 0);
}
#define VMCNT(N) asm volatile("s_waitcnt vmcnt(" #N ")" ::: "memory"); \
                 __builtin_amdgcn_sched_barrier(0)

// ---------------------------------------------------------------------------
// Kernel 0 (16 blocks): block 0 builds env tables (bit-identical values);
// all blocks fill padded lat0 (0) / latf (0.04) border+body.
// ---------------------------------------------------------------------------
__global__ __launch_bounds__(256) void k_init(float* __restrict__ ws) {
    const int tid = threadIdx.x;
    if (blockIdx.x == 0) {
        __shared__ float s_tmp[640];
        __shared__ float s_red[4];
        float m = 0.0f;
        for (int r = tid; r < PATCH; r += 256) {
            int qi = div25(r);
            float di = (float)qi - 12.0f;
            float dj = (float)(r - 25 * qi) - 12.0f;
            float d = sqrtf(di * di + dj * dj);
            float ae = 0.0f, le = 0.0f;
            if (d < 12.5f) {
                float c1 = cosf(d * (PI_F / 25.0f));
                ae = c1 * c1;
                float inh = 0.0f;
                if (d < 4.5f) {
                    float c2 = cosf(d * (PI_F / 9.0f));
                    inh = c2 * c2;
                }
                le = c1 * c1 * (1.0f - inh);
            }
            ws[WS_AE + r] = ae;
            s_tmp[r] = le;
            m = fmaxf(m, le);
        }
        for (int o = 32; o; o >>= 1) m = fmaxf(m, __shfl_down(m, o));
        if (!(tid & 63)) s_red[tid >> 6] = m;
        __syncthreads();
        float inv = 1.0f / fmaxf(fmaxf(s_red[0], s_red[1]),
                                 fmaxf(s_red[2], s_red[3]));
        for (int r = tid; r < PATCH; r += 256) ws[WS_LRI + r] = s_tmp[r] * inv;
    }
    const int gid = blockIdx.x * 256 + tid;
    const int gsz = gridDim.x * 256;
    for (int i = gid; i < 2 * PADA; i += gsz) {
        if (i < PADA) ws[WS_LAT0P + i] = 0.0f;
        else          ws[WS_LATFP + i - PADA] = 0.04f;
    }
}

// ---------------------------------------------------------------------------
// Kernel 1: FUSED tiles + raw_aff + lat0.  1024 blocks; block = 16
// consecutive l (same li) -> x window (2ch x 25 x 40) staged in LDS once:
// the divergent x-gather becomes a dense LDS read.  Each wave owns 4 rows,
// software-pipelined: double-buffered rfs staging via global_load_lds with
// COUNTED vmcnt (T3/T4) -- stage(n+1) stays in flight under consume(n);
// never drains to 0 in the loop (rounds 5/6 drained per row = full latency
// exposed per row = the invariant ~55us).  Consume: dense ds_read + dense
// scalar tile stores.  vmcnt counts derived: 22 stores/row + 5 gld/stage.
// ---------------------------------------------------------------------------
__global__ __launch_bounds__(256) void k_afftiles(const float* __restrict__ x,
                                                  const float* __restrict__ rfs,
                                                  const float* __restrict__ ada,
                                                  float* __restrict__ raw_aff,
                                                  float* __restrict__ tiles,
                                                  float* __restrict__ ws) {
    __shared__ float s_ae[640];
    __shared__ float s_x[2][25][40];
    __shared__ float s_st[4][2][1280];
    const int tid = threadIdx.x, lane = tid & 63, wv = tid >> 6;
    const int blk = blockIdx.x;
    const int li = blk >> 3;
    const int lj0 = (blk & 7) << 4;

    for (int i = tid; i < 625; i += 256) s_ae[i] = ws[WS_AE + i];
    for (int i = tid; i < 2000; i += 256) {
        int c = i >= 1000;
        int rm = i - (c ? 1000 : 0);
        int ki = rm / 40;
        int col = rm - ki * 40;
        s_x[c][ki][col] = x[c * PADA + (li + ki) * PADW + lj0 + col];
    }
    __syncthreads();

    const int tc0 = wv << 2;                   // wave's first col-in-window
    const int l0 = li * 128 + lj0 + tc0;       // wave's first row

    // ---- prologue: the 2 unstaged elems per row + ada, all retired before
    // the pipeline starts (older than stage0 in vmcnt order) ----------------
    float acc_ht[4], ad[4];
#define HT(n) { \
        const int l = l0 + (n); const long B = (long)l * FEAT; \
        const int peel = (l & 1) ? 2 : 0; \
        float a = 0.0f; \
        if (lane < 2) { \
            int f = peel ? lane : (1248 + lane); \
            int c = f >= 625; int r = f - (c ? 625 : 0); \
            int ki = div25(r); int kj = r - 25 * ki; \
            float t = s_x[c][ki][kj + tc0 + (n)] * s_ae[r]; \
            tiles[B + f] = t; \
            a = t * fmaxf(rfs[B + f], 0.0f); \
        } \
        if (!lane) ad[n] = ada[l]; \
        acc_ht[n] = a; }
    HT(0) HT(1) HT(2) HT(3)
#undef HT

    auto stage = [&](int n, float* buf) {
        const int l = l0 + n;
        const long B = (long)l * FEAT;
        const int peel = (l & 1) ? 2 : 0;
        const float* gp = rfs + B + peel + 4 * lane;   // per-lane src
        gld16(gp,        buf);                          // uniform LDS dest
        gld16(gp + 256,  buf + 256);
        gld16(gp + 512,  buf + 512);
        gld16(gp + 768,  buf + 768);
        if (lane < 56) gld16(gp + 1024, buf + 1024);   // 312 f4 = 4*64+56
    };
    auto consume = [&](int n, const float* buf, float accin, float adv) {
        const int l = l0 + n;
        const long B = (long)l * FEAT;
        const int peel = (l & 1) ? 2 : 0;
        const int tc = tc0 + n;
        float acc = accin;
#pragma unroll
        for (int j = 0; j < 20; ++j) {
            int fh = j * 64 + lane;
            if (j < 19 || lane < 32) {                 // fh < 1248
                float rv = buf[fh];                    // dense ds_read_b32
                int f = peel + fh;
                int c = f >= 625;
                int r = f - (c ? 625 : 0);
                int ki = div25(r);
                int kj = r - 25 * ki;
                float t = s_x[c][ki][kj + tc] * s_ae[r];
                tiles[B + f] = t;                      // dense scalar store
                acc += t * fmaxf(rv, 0.0f);
            }
        }
        for (int o = 32; o; o >>= 1) acc += __shfl_down(acc, o);
        if (!lane) {
            raw_aff[l] = acc;
            ws[WS_LAT0P + (li + 12) * PADW + lj0 + tc + 12] =
                fmaxf(acc - adv, 0.0f);
        }
    };

    float* buf0 = &s_st[wv][0][0];
    float* buf1 = &s_st[wv][1][0];
    __builtin_amdgcn_sched_barrier(0);
    stage(0, buf0);
    stage(1, buf1);
    VMCNT(5);                 // stage0 done; stage1 (5) may be in flight
    consume(0, buf0, acc_ht[0], ad[0]);
    stage(2, buf0);
    VMCNT(27);                // stage1 done; stores0(22)+stage2(5) in flight
    consume(1, buf1, acc_ht[1], ad[1]);
    stage(3, buf1);
    VMCNT(27);                // stage2 done; stores1(22)+stage3(5) in flight
    consume(2, buf0, acc_ht[2], ad[2]);
    VMCNT(22);                // stage3 done; stores2(22) in flight
    consume(3, buf1, acc_ht[3], ad[3]);
}

// ---------------------------------------------------------------------------
// Kernel 2: final lat.  Same pipeline shape: block = 16 l, lat0 window
// (25x40 of the padded array) staged in LDS; wave = 4 rows, dbuf lw staging,
// counted vmcnt (3 gld/stage, 2 stores/row).
// ---------------------------------------------------------------------------
__global__ __launch_bounds__(256) void k_lat(const float* __restrict__ raw_aff,
                                             const float* __restrict__ ada,
                                             const float* __restrict__ lw,
                                             float* __restrict__ latf,
                                             float* __restrict__ ws) {
    __shared__ float s_le[640];
    __shared__ float s_g[25][40];
    __shared__ float s_st[4][2][640];
    const int tid = threadIdx.x, lane = tid & 63, wv = tid >> 6;
    const int blk = blockIdx.x;
    const int li = blk >> 3;
    const int lj0 = (blk & 7) << 4;

    for (int i = tid; i < 625; i += 256) s_le[i] = ws[WS_LRI + i];
    for (int i = tid; i < 1000; i += 256) {
        int ki = i / 40;
        int col = i - ki * 40;
        s_g[ki][col] = ws[WS_LAT0P + (li + ki) * PADW + lj0 + col];
    }
    __syncthreads();

    const int tc0 = wv << 2;
    const int l0 = li * 128 + lj0 + tc0;

    float acc_ht[4], ra[4], ad[4];
#define HT(n) { \
        const int l = l0 + (n); const long B = (long)l * PATCH; \
        const int peel = (4 - (l & 3)) & 3; \
        const int fmax4 = (PATCH - peel) & ~3; \
        const int tcnt = (PATCH - peel) & 3; \
        float a = 0.0f; \
        if (lane < peel) { \
            int f = lane; int ki = div25(f); int kj = f - 25 * ki; \
            a += s_g[ki][kj + tc0 + (n)] * s_le[f] * fmaxf(lw[B + f], 0.0f); \
        } \
        if (lane < tcnt) { \
            int f = peel + fmax4 + lane; int ki = div25(f); int kj = f - 25 * ki; \
            a += s_g[ki][kj + tc0 + (n)] * s_le[f] * fmaxf(lw[B + f], 0.0f); \
        } \
        if (!lane) { ra[n] = raw_aff[l]; ad[n] = ada[l]; } \
        acc_ht[n] = a; }
    HT(0) HT(1) HT(2) HT(3)
#undef HT

    auto stage = [&](int n, float* buf) {
        const int l = l0 + n;
        const long B = (long)l * PATCH;
        const int peel = (4 - (l & 3)) & 3;
        const int rem = ((PATCH - peel) >> 2) - 128;   // 27 or 28
        const float* gp = lw + B + peel + 4 * lane;
        gld16(gp,       buf);
        gld16(gp + 256, buf + 256);
        if (lane < rem) gld16(gp + 512, buf + 512);
    };
    auto consume = [&](int n, const float* buf, float accin, float rav,
                       float adv) {
        const int l = l0 + n;
        const int peel = (4 - (l & 3)) & 3;
        const int fmax4 = (PATCH - peel) & ~3;
        const int tc = tc0 + n;
        float acc = accin;
#pragma unroll
        for (int j = 0; j < 10; ++j) {
            int fh = j * 64 + lane;
            if (j < 9 || fh < fmax4) {
                float wval = buf[fh];
                int f = peel + fh;
                int ki = div25(f);
                int kj = f - 25 * ki;
                acc += s_g[ki][kj + tc] * s_le[f] * fmaxf(wval, 0.0f);
            }
        }
        for (int o = 32; o; o >>= 1) acc += __shfl_down(acc, o);
        if (!lane) {
            float aff_l = rav - adv;
            float lat0_l = fmaxf(aff_l, 0.0f);
            float v = (lat0_l - acc) /* *STRENGTH=1 */ + aff_l;
            float lv = tanhf(fmaxf(v, 0.0f));
            latf[l] = lv;
            ws[WS_LATFP + (li + 12) * PADW + lj0 + tc + 12] = lv;
        }
    };

    float* buf0 = &s_st[wv][0][0];
    float* buf1 = &s_st[wv][1][0];
    __builtin_amdgcn_sched_barrier(0);
    stage(0, buf0);
    stage(1, buf1);
    VMCNT(3);                 // stage0 done; stage1 in flight
    consume(0, buf0, acc_ht[0], ra[0], ad[0]);
    stage(2, buf0);
    VMCNT(5);                 // stage1 done; stores0(2)+stage2(3) in flight
    consume(1, buf1, acc_ht[1], ra[1], ad[1]);
    stage(3, buf1);
    VMCNT(5);
    consume(2, buf0, acc_ht[2], ra[2], ad[2]);
    VMCNT(2);                 // stage3 done; stores2(2) in flight
    consume(3, buf1, acc_ht[3], ra[3], ad[3]);
}

// ---------------------------------------------------------------------------
// Kernel 3: corr partials.  Same pipeline on padded latf (border 0.04);
// no in-pipeline stores -> vmcnt(3)/(0).
// ---------------------------------------------------------------------------
__global__ __launch_bounds__(256) void k_corr(const float* __restrict__ latf,
                                              const float* __restrict__ lw,
                                              float* __restrict__ ws) {
    __shared__ float s_le[640];
    __shared__ float s_g[25][40];
    __shared__ float s_st[4][2][640];
    __shared__ float s_red[4];
    const int tid = threadIdx.x, lane = tid & 63, wv = tid >> 6;
    const int blk = blockIdx.x;
    const int li = blk >> 3;
    const int lj0 = (blk & 7) << 4;

    for (int i = tid; i < 625; i += 256) s_le[i] = ws[WS_LRI + i];
    for (int i = tid; i < 1000; i += 256) {
        int ki = i / 40;
        int col = i - ki * 40;
        s_g[ki][col] = ws[WS_LATFP + (li + ki) * PADW + lj0 + col];
    }
    __syncthreads();

    const int tc0 = wv << 2;
    const int l0 = li * 128 + lj0 + tc0;

    float acc_ht[4], lf[4];
#define HT(n) { \
        const int l = l0 + (n); const long B = (long)l * PATCH; \
        const int peel = (4 - (l & 3)) & 3; \
        const int fmax4 = (PATCH - peel) & ~3; \
        const int tcnt = (PATCH - peel) & 3; \
        float a = 0.0f; \
        if (lane < peel) { \
            int f = lane; int ki = div25(f); int kj = f - 25 * ki; \
            a += s_g[ki][kj + tc0 + (n)] * s_le[f] * fmaxf(lw[B + f], 0.0f); \
        } \
        if (lane < tcnt) { \
            int f = peel + fmax4 + lane; int ki = div25(f); int kj = f - 25 * ki; \
            a += s_g[ki][kj + tc0 + (n)] * s_le[f] * fmaxf(lw[B + f], 0.0f); \
        } \
        if (!lane) lf[n] = latf[l]; \
        acc_ht[n] = a; }
    HT(0) HT(1) HT(2) HT(3)
#undef HT

    auto stage = [&](int n, float* buf) {
        const int l = l0 + n;
        const long B = (long)l * PATCH;
        const int peel = (4 - (l & 3)) & 3;
        const int rem = ((PATCH - peel) >> 2) - 128;
        const float* gp = lw + B + peel + 4 * lane;
        gld16(gp,       buf);
        gld16(gp + 256, buf + 256);
        if (lane < rem) gld16(gp + 512, buf + 512);
    };
    float wsum = 0.0f;
    auto consume = [&](int n, const float* buf, float accin, float lfv) {
        const int l = l0 + n;
        const int peel = (4 - (l & 3)) & 3;
        const int fmax4 = (PATCH - peel) & ~3;
        const int tc = tc0 + n;
        float acc = accin;
#pragma unroll
        for (int j = 0; j < 10; ++j) {
            int fh = j * 64 + lane;
            if (j < 9 || fh < fmax4) {
                float wval = buf[fh];
                int f = peel + fh;
                int ki = div25(f);
                int kj = f - 25 * ki;
                acc += s_g[ki][kj + tc] * s_le[f] * fmaxf(wval, 0.0f);
            }
        }
        for (int o = 32; o; o >>= 1) acc += __shfl_down(acc, o);
        if (!lane) wsum += acc * lfv;
    };

    float* buf0 = &s_st[wv][0][0];
    float* buf1 = &s_st[wv][1][0];
    __builtin_amdgcn_sched_barrier(0);
    stage(0, buf0);
    stage(1, buf1);
    VMCNT(3);
    consume(0, buf0, acc_ht[0], lf[0]);
    stage(2, buf0);
    VMCNT(3);
    consume(1, buf1, acc_ht[1], lf[1]);
    stage(3, buf1);
    VMCNT(3);
    consume(2, buf0, acc_ht[2], lf[2]);
    VMCNT(0);
    consume(3, buf1, acc_ht[3], lf[3]);

    if (!lane) s_red[wv] = wsum;
    __syncthreads();
    if (!tid)
        ws[WS_PART + blk] = s_red[0] + s_red[1] + s_red[2] + s_red[3];
}

// ---------------------------------------------------------------------------
// Kernel 4: deterministic sum of 1024 partials -> corr scalar.
// ---------------------------------------------------------------------------
__global__ __launch_bounds__(256) void k_reduce(const float* __restrict__ ws,
                                                float* __restrict__ corr) {
    __shared__ float s_red[4];
    const int tid = threadIdx.x;
    const int lane = tid & 63, wv = tid >> 6;
    float acc = 0.0f;
    for (int i = tid; i < NPART; i += 256) acc += ws[WS_PART + i];
    for (int o = 32; o; o >>= 1) acc += __shfl_down(acc, o);
    if (!lane) s_red[wv] = acc;
    __syncthreads();
    if (!tid) corr[0] = s_red[0] + s_red[1] + s_red[2] + s_red[3];
}

// ---------------------------------------------------------------------------
// d_out layout (flat, return order):
//   [0, 16384)              raw_aff   [1,1,128,128]
//   [16384, 32768)          lat       [1,1,128,128]
//   [32768]                 lat_correlations (scalar)
//   [32769, 32769+20480000) tiles     [16384, 1, 1250]
// ---------------------------------------------------------------------------
extern "C" void kernel_launch(void* const* d_in, const int* in_sizes, int n_in,
                              void* d_out, int out_size, void* d_ws, size_t ws_size,
                              hipStream_t stream) {
    const float* x   = (const float*)d_in[0];   // [1,2,152,152]
    const float* rfs = (const float*)d_in[1];   // [16384,1250,1]
    const float* lw  = (const float*)d_in[2];   // [16384,625,1]
    const float* ada = (const float*)d_in[3];   // [1,1,128,128]

    float* out      = (float*)d_out;
    float* raw_aff  = out;
    float* latf     = out + S * S;
    float* corr     = out + 2 * S * S;
    float* tiles    = out + 2 * S * S + 1;
    float* ws       = (float*)d_ws;

    k_init<<<16, 256, 0, stream>>>(ws);
    k_afftiles<<<1024, 256, 0, stream>>>(x, rfs, ada, raw_aff, tiles, ws);
    k_lat<<<1024, 256, 0, stream>>>(raw_aff, ada, lw, latf, ws);
    k_corr<<<1024, 256, 0, stream>>>(latf, lw, ws);
    k_reduce<<<1, 256, 0, stream>>>(ws, corr);
}

// Round 8
// 223.594 us; speedup vs baseline: 1.0171x; 1.0078x over previous
//
#include <hip/hip_runtime.h>
#include <math.h>

#define S 128
#define KA 25
#define PATCH 625
#define FEAT 1250
#define PI_F 3.14159265358979323846f
#define PADW 152             // 128 + 24; ALSO the x row stride (152x152 input)
#define PADA (PADW * PADW)   // 23104

// d_ws layout (floats):
//   [0, 625)             LRI env, LINEAR (k_lat/k_corr consume f-dense)
//   [640, 1280)          AFF env, residue-split slot(r)=(r&3)*160+(r>>2)
//                        (k_aff walks r at stride 4 -> split is conflict-free)
//   [1280, 24384)        padded lat0, 152x152, border 0
//   [24384, 47488)       padded latf, 152x152, border HOMEO_TARGET
//   [47488, 48512)       per-block corr partials (1024)
#define WS_LRI 0
#define WS_AE 640
#define WS_LAT0P 1280
#define WS_LATFP 24384
#define WS_PART 47488
#define NPART 1024

// floor(r/25) for r in [0,625): exact (25*10486 = 2^18+6).
__device__ __forceinline__ int div25(int r) { return (r * 10486) >> 18; }
__device__ __forceinline__ int eslot(int r) { return (r & 3) * 160 + (r >> 2); }

// Async global->LDS, 16B/lane (wave-uniform LDS base, per-lane global src).
__device__ __forceinline__ void gld16(const float* g, float* l) {
    __builtin_amdgcn_global_load_lds(
        (const __attribute__((address_space(1))) void*)g,
        (__attribute__((address_space(3))) void*)l, 16, 0, 0);
}
#define VMCNT(N) asm volatile("s_waitcnt vmcnt(" #N ")" ::: "memory"); \
                 __builtin_amdgcn_sched_barrier(0)

// ---------------------------------------------------------------------------
// Kernel 0 (16 blocks): block 0 builds env tables (bit-identical values);
// all blocks fill padded lat0 (0) / latf (0.04).
// ---------------------------------------------------------------------------
__global__ __launch_bounds__(256) void k_init(float* __restrict__ ws) {
    const int tid = threadIdx.x;
    if (blockIdx.x == 0) {
        __shared__ float s_tmp[640];
        __shared__ float s_red[4];
        float m = 0.0f;
        for (int r = tid; r < PATCH; r += 256) {
            int qi = div25(r);
            float di = (float)qi - 12.0f;
            float dj = (float)(r - 25 * qi) - 12.0f;
            float d = sqrtf(di * di + dj * dj);
            float ae = 0.0f, le = 0.0f;
            if (d < 12.5f) {
                float c1 = cosf(d * (PI_F / 25.0f));
                ae = c1 * c1;
                float inh = 0.0f;
                if (d < 4.5f) {
                    float c2 = cosf(d * (PI_F / 9.0f));
                    inh = c2 * c2;
                }
                le = c1 * c1 * (1.0f - inh);
            }
            ws[WS_AE + eslot(r)] = ae;       // residue-split for k_aff
            s_tmp[r] = le;
            m = fmaxf(m, le);
        }
        for (int o = 32; o; o >>= 1) m = fmaxf(m, __shfl_down(m, o));
        if (!(tid & 63)) s_red[tid >> 6] = m;
        __syncthreads();
        float inv = 1.0f / fmaxf(fmaxf(s_red[0], s_red[1]),
                                 fmaxf(s_red[2], s_red[3]));
        for (int r = tid; r < PATCH; r += 256) ws[WS_LRI + r] = s_tmp[r] * inv;
    }
    const int gid = blockIdx.x * 256 + tid;
    const int gsz = gridDim.x * 256;
    for (int i = gid; i < 2 * PADA; i += gsz) {
        if (i < PADA) ws[WS_LAT0P + i] = 0.0f;
        else          ws[WS_LATFP + i - PADA] = 0.04f;
    }
}

// ---------------------------------------------------------------------------
// Kernel 1: raw_aff + lat0 + c=0 HALF of tiles.  Round-5 structure (the
// best-measured: one wave per row, float4 rfs reads, high occupancy) with
// the c>=625 stores REMOVED: 7 structures showed this kernel's mixed
// R+W stream is service-rate-bound at ~2.2 TB/s, so the write work is
// redistributed to the read-light k_lat/k_corr (where r5 showed overlapped
// writes are nearly free).  acc math untouched -> bit-identical outputs.
// ---------------------------------------------------------------------------
__global__ __launch_bounds__(256) void k_aff(const float* __restrict__ x,
                                             const float* __restrict__ rfs,
                                             const float* __restrict__ ada,
                                             float* __restrict__ raw_aff,
                                             float* __restrict__ tiles,
                                             float* __restrict__ ws) {
    __shared__ float s_ae[640];
    const int tid = threadIdx.x;
    for (int i = tid; i < 640; i += 256) s_ae[i] = ws[WS_AE + i];
    __syncthreads();

    const int lane = tid & 63;
    const int l = blockIdx.x * 4 + (tid >> 6);     // 16384 waves, 1 row each
    const int li = l >> 7, lj = l & 127;
    const int wb = li * PADW + lj;                 // x row stride is also 152
    const long B = (long)l * FEAT;
    const int peel = (l & 1) ? 2 : 0;              // (1250*l) mod 4 = 2*(l&1)

    float acc = 0.0f;
    if (lane < peel) {                              // l odd: f=0,1 (c=0: store)
        int f = lane;
        float t = x[wb + f] * s_ae[eslot(f)];
        tiles[B + f] = t;
        acc += t * fmaxf(rfs[B + f], 0.0f);
    }

    const float* __restrict__ rb = rfs + B + peel;
    const float4 rv0 = *reinterpret_cast<const float4*>(rb + 4 * lane);
    const float4 rv1 = *reinterpret_cast<const float4*>(rb + 4 * (lane + 64));
    const float4 rv2 = *reinterpret_cast<const float4*>(rb + 4 * (lane + 128));
    const float4 rv3 = *reinterpret_cast<const float4*>(rb + 4 * (lane + 192));
    float4 rv4 = {0.0f, 0.0f, 0.0f, 0.0f};
    if (lane < 56) rv4 = *reinterpret_cast<const float4*>(rb + 4 * (lane + 256));

    auto consume = [&](const float4& rv, int k) {
        const int f0 = peel + 4 * k;
#pragma unroll
        for (int j = 0; j < 4; ++j) {
            int f = f0 + j;
            int c = (f >= PATCH) ? 1 : 0;
            int r = f - c * PATCH;
            float t = x[c * PADA + wb + r + 127 * div25(r)] * s_ae[eslot(r)];
            if (f < PATCH) tiles[B + f] = t;       // c=0 half only
            acc += t * fmaxf((&rv.x)[j], 0.0f);
        }
    };
    consume(rv0, lane);
    consume(rv1, lane + 64);
    consume(rv2, lane + 128);
    consume(rv3, lane + 192);
    if (lane < 56) consume(rv4, lane + 256);

    if (lane < 2 - peel) {                          // l even: f=1248,1249 (c=1,
        int f = 1248 + lane;                        //  acc only, no store)
        int r = f - PATCH;
        acc += x[PADA + wb + r + 127 * div25(r)] * s_ae[eslot(r)]
               * fmaxf(rfs[B + f], 0.0f);
    }

    for (int o = 32; o; o >>= 1) acc += __shfl_down(acc, o);
    if (!lane) {
        raw_aff[l] = acc;
        ws[WS_LAT0P + (li + 12) * PADW + (lj + 12)] = fmaxf(acc - ada[l], 0.0f);
    }
}

// ---------------------------------------------------------------------------
// Tiles c=1 epilogue, shared by k_lat (even li) / k_corr (odd li).  Reuses
// the wave staging LDS (s_st, >=1640 floats) for the AFF env + x[1] window.
// Each block writes its own 16 rows' c=1 half (16*625*4 B = 40 KB).
// ---------------------------------------------------------------------------
__device__ __forceinline__ void tiles_c1_epilogue(
        const float* __restrict__ x, float* __restrict__ tiles,
        const float* __restrict__ ws, float* e_ae, float* e_x1,
        int li, int lj0, int tc0, int lane, int tid) {
    for (int i = tid; i < 640; i += 256) e_ae[i] = ws[WS_AE + i];
    for (int i = tid; i < 1000; i += 256) {
        int ki = i / 40, col = i - ki * 40;
        e_x1[i] = x[PADA + (li + ki) * PADW + lj0 + col];   // L2-hot (92 KB)
    }
    __syncthreads();
#pragma unroll
    for (int n = 0; n < 4; ++n) {
        const int tc = tc0 + n;
        const long B = (long)(li * 128 + lj0 + tc) * FEAT + PATCH;
#pragma unroll
        for (int j = 0; j < 10; ++j) {
            int r = j * 64 + lane;
            if (j < 9 || lane < 49) {              // 625 = 9*64 + 49
                int ki = div25(r), kj = r - 25 * ki;
                tiles[B + r] = e_x1[ki * 40 + kj + tc] * e_ae[eslot(r)];
            }
        }
    }
}

// ---------------------------------------------------------------------------
// Kernel 2: final lat (round-7 pipeline: block = 16 l, lat0 window in LDS,
// wave = 4 rows, dbuf lw staging, counted vmcnt) + c=1 tiles epilogue for
// even-li blocks (20.5 MB of writes hidden under the lw read latency).
// ---------------------------------------------------------------------------
__global__ __launch_bounds__(256) void k_lat(const float* __restrict__ raw_aff,
                                             const float* __restrict__ ada,
                                             const float* __restrict__ lw,
                                             const float* __restrict__ x,
                                             float* __restrict__ latf,
                                             float* __restrict__ tiles,
                                             float* __restrict__ ws) {
    __shared__ float s_le[640];
    __shared__ float s_g[25][40];
    __shared__ float s_st[4][2][640];
    const int tid = threadIdx.x, lane = tid & 63, wv = tid >> 6;
    const int blk = blockIdx.x;
    const int li = blk >> 3;
    const int lj0 = (blk & 7) << 4;

    for (int i = tid; i < 625; i += 256) s_le[i] = ws[WS_LRI + i];
    for (int i = tid; i < 1000; i += 256) {
        int ki = i / 40;
        int col = i - ki * 40;
        s_g[ki][col] = ws[WS_LAT0P + (li + ki) * PADW + lj0 + col];
    }
    __syncthreads();

    const int tc0 = wv << 2;
    const int l0 = li * 128 + lj0 + tc0;

    float acc_ht[4], ra[4], ad[4];
#define HT(n) { \
        const int l = l0 + (n); const long B = (long)l * PATCH; \
        const int peel = (4 - (l & 3)) & 3; \
        const int fmax4 = (PATCH - peel) & ~3; \
        const int tcnt = (PATCH - peel) & 3; \
        float a = 0.0f; \
        if (lane < peel) { \
            int f = lane; int ki = div25(f); int kj = f - 25 * ki; \
            a += s_g[ki][kj + tc0 + (n)] * s_le[f] * fmaxf(lw[B + f], 0.0f); \
        } \
        if (lane < tcnt) { \
            int f = peel + fmax4 + lane; int ki = div25(f); int kj = f - 25 * ki; \
            a += s_g[ki][kj + tc0 + (n)] * s_le[f] * fmaxf(lw[B + f], 0.0f); \
        } \
        if (!lane) { ra[n] = raw_aff[l]; ad[n] = ada[l]; } \
        acc_ht[n] = a; }
    HT(0) HT(1) HT(2) HT(3)
#undef HT

    auto stage = [&](int n, float* buf) {
        const int l = l0 + n;
        const long B = (long)l * PATCH;
        const int peel = (4 - (l & 3)) & 3;
        const int rem = ((PATCH - peel) >> 2) - 128;   // 27 or 28
        const float* gp = lw + B + peel + 4 * lane;
        gld16(gp,       buf);
        gld16(gp + 256, buf + 256);
        if (lane < rem) gld16(gp + 512, buf + 512);
    };
    auto consume = [&](int n, const float* buf, float accin, float rav,
                       float adv) {
        const int l = l0 + n;
        const int peel = (4 - (l & 3)) & 3;
        const int fmax4 = (PATCH - peel) & ~3;
        const int tc = tc0 + n;
        float acc = accin;
#pragma unroll
        for (int j = 0; j < 10; ++j) {
            int fh = j * 64 + lane;
            if (j < 9 || fh < fmax4) {
                float wval = buf[fh];
                int f = peel + fh;
                int ki = div25(f);
                int kj = f - 25 * ki;
                acc += s_g[ki][kj + tc] * s_le[f] * fmaxf(wval, 0.0f);
            }
        }
        for (int o = 32; o; o >>= 1) acc += __shfl_down(acc, o);
        if (!lane) {
            float aff_l = rav - adv;
            float lat0_l = fmaxf(aff_l, 0.0f);
            float v = (lat0_l - acc) /* *STRENGTH=1 */ + aff_l;
            float lv = tanhf(fmaxf(v, 0.0f));
            latf[l] = lv;
            ws[WS_LATFP + (li + 12) * PADW + lj0 + tc + 12] = lv;
        }
    };

    float* buf0 = &s_st[wv][0][0];
    float* buf1 = &s_st[wv][1][0];
    __builtin_amdgcn_sched_barrier(0);
    stage(0, buf0);
    stage(1, buf1);
    VMCNT(3);                 // stage0 done; stage1 in flight
    consume(0, buf0, acc_ht[0], ra[0], ad[0]);
    stage(2, buf0);
    VMCNT(5);                 // stage1 done; stores0(2)+stage2(3) in flight
    consume(1, buf1, acc_ht[1], ra[1], ad[1]);
    stage(3, buf1);
    VMCNT(5);
    consume(2, buf0, acc_ht[2], ra[2], ad[2]);
    VMCNT(2);                 // stage3 done; stores2(2) in flight
    consume(3, buf1, acc_ht[3], ra[3], ad[3]);

    if ((li & 1) == 0) {      // even-li blocks write their c=1 tiles half
        __syncthreads();      // s_st free for reuse
        tiles_c1_epilogue(x, tiles, ws, &s_st[0][0][0], &s_st[1][0][0],
                          li, lj0, tc0, lane, tid);
    }
}

// ---------------------------------------------------------------------------
// Kernel 3: corr partials (round-7 pipeline on padded latf) + c=1 tiles
// epilogue for odd-li blocks.
// ---------------------------------------------------------------------------
__global__ __launch_bounds__(256) void k_corr(const float* __restrict__ latf,
                                              const float* __restrict__ lw,
                                              const float* __restrict__ x,
                                              float* __restrict__ tiles,
                                              float* __restrict__ ws) {
    __shared__ float s_le[640];
    __shared__ float s_g[25][40];
    __shared__ float s_st[4][2][640];
    __shared__ float s_red[4];
    const int tid = threadIdx.x, lane = tid & 63, wv = tid >> 6;
    const int blk = blockIdx.x;
    const int li = blk >> 3;
    const int lj0 = (blk & 7) << 4;

    for (int i = tid; i < 625; i += 256) s_le[i] = ws[WS_LRI + i];
    for (int i = tid; i < 1000; i += 256) {
        int ki = i / 40;
        int col = i - ki * 40;
        s_g[ki][col] = ws[WS_LATFP + (li + ki) * PADW + lj0 + col];
    }
    __syncthreads();

    const int tc0 = wv << 2;
    const int l0 = li * 128 + lj0 + tc0;

    float acc_ht[4], lf[4];
#define HT(n) { \
        const int l = l0 + (n); const long B = (long)l * PATCH; \
        const int peel = (4 - (l & 3)) & 3; \
        const int fmax4 = (PATCH - peel) & ~3; \
        const int tcnt = (PATCH - peel) & 3; \
        float a = 0.0f; \
        if (lane < peel) { \
            int f = lane; int ki = div25(f); int kj = f - 25 * ki; \
            a += s_g[ki][kj + tc0 + (n)] * s_le[f] * fmaxf(lw[B + f], 0.0f); \
        } \
        if (lane < tcnt) { \
            int f = peel + fmax4 + lane; int ki = div25(f); int kj = f - 25 * ki; \
            a += s_g[ki][kj + tc0 + (n)] * s_le[f] * fmaxf(lw[B + f], 0.0f); \
        } \
        if (!lane) lf[n] = latf[l]; \
        acc_ht[n] = a; }
    HT(0) HT(1) HT(2) HT(3)
#undef HT

    auto stage = [&](int n, float* buf) {
        const int l = l0 + n;
        const long B = (long)l * PATCH;
        const int peel = (4 - (l & 3)) & 3;
        const int rem = ((PATCH - peel) >> 2) - 128;
        const float* gp = lw + B + peel + 4 * lane;
        gld16(gp,       buf);
        gld16(gp + 256, buf + 256);
        if (lane < rem) gld16(gp + 512, buf + 512);
    };
    float wsum = 0.0f;
    auto consume = [&](int n, const float* buf, float accin, float lfv) {
        const int l = l0 + n;
        const int peel = (4 - (l & 3)) & 3;
        const int fmax4 = (PATCH - peel) & ~3;
        const int tc = tc0 + n;
        float acc = accin;
#pragma unroll
        for (int j = 0; j < 10; ++j) {
            int fh = j * 64 + lane;
            if (j < 9 || fh < fmax4) {
                float wval = buf[fh];
                int f = peel + fh;
                int ki = div25(f);
                int kj = f - 25 * ki;
                acc += s_g[ki][kj + tc] * s_le[f] * fmaxf(wval, 0.0f);
            }
        }
        for (int o = 32; o; o >>= 1) acc += __shfl_down(acc, o);
        if (!lane) wsum += acc * lfv;
    };

    float* buf0 = &s_st[wv][0][0];
    float* buf1 = &s_st[wv][1][0];
    __builtin_amdgcn_sched_barrier(0);
    stage(0, buf0);
    stage(1, buf1);
    VMCNT(3);
    consume(0, buf0, acc_ht[0], lf[0]);
    stage(2, buf0);
    VMCNT(3);
    consume(1, buf1, acc_ht[1], lf[1]);
    stage(3, buf1);
    VMCNT(3);
    consume(2, buf0, acc_ht[2], lf[2]);
    VMCNT(0);
    consume(3, buf1, acc_ht[3], lf[3]);

    if (!lane) s_red[wv] = wsum;
    __syncthreads();
    if (!tid)
        ws[WS_PART + blk] = s_red[0] + s_red[1] + s_red[2] + s_red[3];

    if ((li & 1) == 1) {      // odd-li blocks write their c=1 tiles half
        __syncthreads();      // s_st free for reuse
        tiles_c1_epilogue(x, tiles, ws, &s_st[0][0][0], &s_st[1][0][0],
                          li, lj0, tc0, lane, tid);
    }
}

// ---------------------------------------------------------------------------
// Kernel 4: deterministic sum of 1024 partials -> corr scalar.
// ---------------------------------------------------------------------------
__global__ __launch_bounds__(256) void k_reduce(const float* __restrict__ ws,
                                                float* __restrict__ corr) {
    __shared__ float s_red[4];
    const int tid = threadIdx.x;
    const int lane = tid & 63, wv = tid >> 6;
    float acc = 0.0f;
    for (int i = tid; i < NPART; i += 256) acc += ws[WS_PART + i];
    for (int o = 32; o; o >>= 1) acc += __shfl_down(acc, o);
    if (!lane) s_red[wv] = acc;
    __syncthreads();
    if (!tid) corr[0] = s_red[0] + s_red[1] + s_red[2] + s_red[3];
}

// ---------------------------------------------------------------------------
// d_out layout (flat, return order):
//   [0, 16384)              raw_aff   [1,1,128,128]
//   [16384, 32768)          lat       [1,1,128,128]
//   [32768]                 lat_correlations (scalar)
//   [32769, 32769+20480000) tiles     [16384, 1, 1250]
// ---------------------------------------------------------------------------
extern "C" void kernel_launch(void* const* d_in, const int* in_sizes, int n_in,
                              void* d_out, int out_size, void* d_ws, size_t ws_size,
                              hipStream_t stream) {
    const float* x   = (const float*)d_in[0];   // [1,2,152,152]
    const float* rfs = (const float*)d_in[1];   // [16384,1250,1]
    const float* lw  = (const float*)d_in[2];   // [16384,625,1]
    const float* ada = (const float*)d_in[3];   // [1,1,128,128]

    float* out      = (float*)d_out;
    float* raw_aff  = out;
    float* latf     = out + S * S;
    float* corr     = out + 2 * S * S;
    float* tiles    = out + 2 * S * S + 1;
    float* ws       = (float*)d_ws;

    k_init<<<16, 256, 0, stream>>>(ws);
    k_aff<<<4096, 256, 0, stream>>>(x, rfs, ada, raw_aff, tiles, ws);
    k_lat<<<1024, 256, 0, stream>>>(raw_aff, ada, lw, x, latf, tiles, ws);
    k_corr<<<1024, 256, 0, stream>>>(latf, lw, x, tiles, ws);
    k_reduce<<<1, 256, 0, stream>>>(ws, corr);
}

// Round 9
// 214.875 us; speedup vs baseline: 1.0584x; 1.0406x over previous
//
#include <hip/hip_runtime.h>
#include <math.h>

#define S 128
#define KA 25
#define PATCH 625
#define FEAT 1250
#define PI_F 3.14159265358979323846f
#define PADW 152             // 128 + 24; ALSO the x row stride (152x152 input)
#define PADA (PADW * PADW)   // 23104

// d_ws layout (floats):
//   [0, 625)             LRI env, LINEAR
//   [640, 1280)          AFF env, residue-split slot(r)=(r&3)*160+(r>>2)
//   [1280, 24384)        padded lat0, 152x152, border 0
//   [24384, 47488)       padded latf, 152x152, border HOMEO_TARGET
//   [47488, 48512)       per-block corr partials (1024)
//   [48512, 49137)       AFF env, LINEAR (for the tiles epilogues)
#define WS_LRI 0
#define WS_AE 640
#define WS_LAT0P 1280
#define WS_LATFP 24384
#define WS_PART 47488
#define WS_AEL 48512
#define NPART 1024

// floor(r/25) for r in [0,625): exact (25*10486 = 2^18+6).
__device__ __forceinline__ int div25(int r) { return (r * 10486) >> 18; }
__device__ __forceinline__ int eslot(int r) { return (r & 3) * 160 + (r >> 2); }

// Async global->LDS, 16B/lane (wave-uniform LDS base, per-lane global src).
__device__ __forceinline__ void gld16(const float* g, float* l) {
    __builtin_amdgcn_global_load_lds(
        (const __attribute__((address_space(1))) void*)g,
        (__attribute__((address_space(3))) void*)l, 16, 0, 0);
}
#define VMCNT(N) asm volatile("s_waitcnt vmcnt(" #N ")" ::: "memory"); \
                 __builtin_amdgcn_sched_barrier(0)

// ---------------------------------------------------------------------------
// Kernel 0 (16 blocks): block 0 builds env tables (bit-identical values);
// all blocks fill padded lat0 (0) / latf (0.04).
// ---------------------------------------------------------------------------
__global__ __launch_bounds__(256) void k_init(float* __restrict__ ws) {
    const int tid = threadIdx.x;
    if (blockIdx.x == 0) {
        __shared__ float s_tmp[640];
        __shared__ float s_red[4];
        float m = 0.0f;
        for (int r = tid; r < PATCH; r += 256) {
            int qi = div25(r);
            float di = (float)qi - 12.0f;
            float dj = (float)(r - 25 * qi) - 12.0f;
            float d = sqrtf(di * di + dj * dj);
            float ae = 0.0f, le = 0.0f;
            if (d < 12.5f) {
                float c1 = cosf(d * (PI_F / 25.0f));
                ae = c1 * c1;
                float inh = 0.0f;
                if (d < 4.5f) {
                    float c2 = cosf(d * (PI_F / 9.0f));
                    inh = c2 * c2;
                }
                le = c1 * c1 * (1.0f - inh);
            }
            ws[WS_AE + eslot(r)] = ae;       // residue-split for k_aff
            ws[WS_AEL + r] = ae;             // linear for the epilogues
            s_tmp[r] = le;
            m = fmaxf(m, le);
        }
        for (int o = 32; o; o >>= 1) m = fmaxf(m, __shfl_down(m, o));
        if (!(tid & 63)) s_red[tid >> 6] = m;
        __syncthreads();
        float inv = 1.0f / fmaxf(fmaxf(s_red[0], s_red[1]),
                                 fmaxf(s_red[2], s_red[3]));
        for (int r = tid; r < PATCH; r += 256) ws[WS_LRI + r] = s_tmp[r] * inv;
    }
    const int gid = blockIdx.x * 256 + tid;
    const int gsz = gridDim.x * 256;
    for (int i = gid; i < 2 * PADA; i += gsz) {
        if (i < PADA) ws[WS_LAT0P + i] = 0.0f;
        else          ws[WS_LATFP + i - PADA] = 0.04f;
    }
}

// ---------------------------------------------------------------------------
// Kernel 1: PURE-READ raw_aff + lat0.  4096 blocks; block = 4 consecutive l
// (one per wave).  The x window (2ch x 25 x 28) is staged per block in a
// COLUMN-RESIDUE-SPLIT LDS layout: slot(col) = (col&3)*7 + (col>>2), so the
// consume loop's stride-4-lane access is bank-stride-1 (~2-way worst = free).
// This kills the per-element global x-gather (~60 cache lines / instr, ~20
// instr/row) that saturated the TA pipe in every previous round -- the real
// reason MLP/occupancy/vmcnt changes never moved the needle.  rfs is read
// with aligned float4 register loads (round-5 structure, high TLP).  NO
// tiles stores here (they were 25%-density scatters; moved to coalesced
// epilogues in k_lat/k_corr).  acc order unchanged -> bit-identical.
// ---------------------------------------------------------------------------
__global__ __launch_bounds__(256) void k_aff(const float* __restrict__ x,
                                             const float* __restrict__ rfs,
                                             const float* __restrict__ ada,
                                             float* __restrict__ raw_aff,
                                             float* __restrict__ ws) {
    __shared__ float s_ae[640];
    __shared__ float s_x[2][25][28];   // [c][ki][(col&3)*7 + (col>>2)]
    const int tid = threadIdx.x, lane = tid & 63, wv = tid >> 6;
    const int blk = blockIdx.x;
    const int li = blk >> 5;
    const int lj0 = (blk & 31) << 2;

    for (int i = tid; i < 640; i += 256) s_ae[i] = ws[WS_AE + i];
    for (int i = tid; i < 1400; i += 256) {
        int c = i >= 700;
        int rm = i - c * 700;
        int ki = rm / 28;
        int col = rm - ki * 28;
        s_x[c][ki][(col & 3) * 7 + (col >> 2)] =
            x[c * PADA + (li + ki) * PADW + lj0 + col];
    }
    __syncthreads();

    const int tc = wv;                       // wave owns one row
    const int l = li * 128 + lj0 + tc;
    const long B = (long)l * FEAT;
    const int peel = (l & 1) ? 2 : 0;        // (1250*l) mod 4 = 2*(l&1)

    float acc = 0.0f;
    if (lane < peel) {                        // l odd: f=0,1 (c=0, ki=0)
        int f = lane;
        int col = f + tc;
        acc += s_x[0][0][(col & 3) * 7 + (col >> 2)] * s_ae[eslot(f)]
               * fmaxf(rfs[B + f], 0.0f);
    }

    const float* __restrict__ rb = rfs + B + peel;
    const float4 rv0 = *reinterpret_cast<const float4*>(rb + 4 * lane);
    const float4 rv1 = *reinterpret_cast<const float4*>(rb + 4 * (lane + 64));
    const float4 rv2 = *reinterpret_cast<const float4*>(rb + 4 * (lane + 128));
    const float4 rv3 = *reinterpret_cast<const float4*>(rb + 4 * (lane + 192));
    float4 rv4 = {0.0f, 0.0f, 0.0f, 0.0f};
    if (lane < 56) rv4 = *reinterpret_cast<const float4*>(rb + 4 * (lane + 256));

    auto consume = [&](const float4& rv, int k) {
        const int f0 = peel + 4 * k;
#pragma unroll
        for (int j = 0; j < 4; ++j) {
            int f = f0 + j;
            int c = (f >= PATCH) ? 1 : 0;
            int r = f - c * PATCH;
            int ki = div25(r);
            int col = r - 25 * ki + tc;
            float t = s_x[c][ki][(col & 3) * 7 + (col >> 2)] * s_ae[eslot(r)];
            acc += t * fmaxf((&rv.x)[j], 0.0f);
        }
    };
    consume(rv0, lane);
    consume(rv1, lane + 64);
    consume(rv2, lane + 128);
    consume(rv3, lane + 192);
    if (lane < 56) consume(rv4, lane + 256);

    if (lane < 2 - peel) {                    // l even: f=1248,1249 (c=1)
        int f = 1248 + lane;
        int r = f - PATCH;
        int ki = div25(r);
        int col = r - 25 * ki + tc;
        acc += s_x[1][ki][(col & 3) * 7 + (col >> 2)] * s_ae[eslot(r)]
               * fmaxf(rfs[B + f], 0.0f);
    }

    for (int o = 32; o; o >>= 1) acc += __shfl_down(acc, o);
    if (!lane) {
        raw_aff[l] = acc;
        ws[WS_LAT0P + (li + 12) * PADW + (lj0 + tc + 12)] =
            fmaxf(acc - ada[l], 0.0f);
    }
}

// ---------------------------------------------------------------------------
// Tiles epilogue (channel cc): lane-contiguous scalar stores (256 B/instr,
// full density, alignment-agnostic), linear env (conflict-free stride-1 LDS),
// x window L2-hot.  k_lat runs cc=0, k_corr runs cc=1; together they cover
// all of tiles.  Reuses the wave staging LDS as scratch.
// ---------------------------------------------------------------------------
__device__ __forceinline__ void tiles_epilogue(
        const float* __restrict__ x, float* __restrict__ tiles,
        const float* __restrict__ ws, float* e_ae, float* e_x,
        int cc, int li, int lj0, int tc0, int lane, int tid) {
    for (int i = tid; i < 625; i += 256) e_ae[i] = ws[WS_AEL + i];
    for (int i = tid; i < 1000; i += 256) {
        int ki = i / 40, col = i - ki * 40;
        e_x[i] = x[cc * PADA + (li + ki) * PADW + lj0 + col];
    }
    __syncthreads();
#pragma unroll
    for (int n = 0; n < 4; ++n) {
        const int tc = tc0 + n;
        const long B = (long)(li * 128 + lj0 + tc) * FEAT + cc * PATCH;
#pragma unroll
        for (int j = 0; j < 10; ++j) {
            int r = j * 64 + lane;
            if (j < 9 || lane < 49) {          // 625 = 9*64 + 49
                int ki = div25(r), kj = r - 25 * ki;
                tiles[B + r] = e_x[ki * 40 + kj + tc] * e_ae[r];
            }
        }
    }
}

// ---------------------------------------------------------------------------
// Kernel 2: final lat (round-7 pipeline: block = 16 l, lat0 window in LDS,
// wave = 4 rows, dbuf lw staging, counted vmcnt) + c=0 tiles epilogue.
// ---------------------------------------------------------------------------
__global__ __launch_bounds__(256) void k_lat(const float* __restrict__ raw_aff,
                                             const float* __restrict__ ada,
                                             const float* __restrict__ lw,
                                             const float* __restrict__ x,
                                             float* __restrict__ latf,
                                             float* __restrict__ tiles,
                                             float* __restrict__ ws) {
    __shared__ float s_le[640];
    __shared__ float s_g[25][40];
    __shared__ float s_st[4][2][640];
    const int tid = threadIdx.x, lane = tid & 63, wv = tid >> 6;
    const int blk = blockIdx.x;
    const int li = blk >> 3;
    const int lj0 = (blk & 7) << 4;

    for (int i = tid; i < 625; i += 256) s_le[i] = ws[WS_LRI + i];
    for (int i = tid; i < 1000; i += 256) {
        int ki = i / 40;
        int col = i - ki * 40;
        s_g[ki][col] = ws[WS_LAT0P + (li + ki) * PADW + lj0 + col];
    }
    __syncthreads();

    const int tc0 = wv << 2;
    const int l0 = li * 128 + lj0 + tc0;

    float acc_ht[4], ra[4], ad[4];
#define HT(n) { \
        const int l = l0 + (n); const long B = (long)l * PATCH; \
        const int peel = (4 - (l & 3)) & 3; \
        const int fmax4 = (PATCH - peel) & ~3; \
        const int tcnt = (PATCH - peel) & 3; \
        float a = 0.0f; \
        if (lane < peel) { \
            int f = lane; int ki = div25(f); int kj = f - 25 * ki; \
            a += s_g[ki][kj + tc0 + (n)] * s_le[f] * fmaxf(lw[B + f], 0.0f); \
        } \
        if (lane < tcnt) { \
            int f = peel + fmax4 + lane; int ki = div25(f); int kj = f - 25 * ki; \
            a += s_g[ki][kj + tc0 + (n)] * s_le[f] * fmaxf(lw[B + f], 0.0f); \
        } \
        if (!lane) { ra[n] = raw_aff[l]; ad[n] = ada[l]; } \
        acc_ht[n] = a; }
    HT(0) HT(1) HT(2) HT(3)
#undef HT

    auto stage = [&](int n, float* buf) {
        const int l = l0 + n;
        const long B = (long)l * PATCH;
        const int peel = (4 - (l & 3)) & 3;
        const int rem = ((PATCH - peel) >> 2) - 128;   // 27 or 28
        const float* gp = lw + B + peel + 4 * lane;
        gld16(gp,       buf);
        gld16(gp + 256, buf + 256);
        if (lane < rem) gld16(gp + 512, buf + 512);
    };
    auto consume = [&](int n, const float* buf, float accin, float rav,
                       float adv) {
        const int l = l0 + n;
        const int peel = (4 - (l & 3)) & 3;
        const int fmax4 = (PATCH - peel) & ~3;
        const int tc = tc0 + n;
        float acc = accin;
#pragma unroll
        for (int j = 0; j < 10; ++j) {
            int fh = j * 64 + lane;
            if (j < 9 || fh < fmax4) {
                float wval = buf[fh];
                int f = peel + fh;
                int ki = div25(f);
                int kj = f - 25 * ki;
                acc += s_g[ki][kj + tc] * s_le[f] * fmaxf(wval, 0.0f);
            }
        }
        for (int o = 32; o; o >>= 1) acc += __shfl_down(acc, o);
        if (!lane) {
            float aff_l = rav - adv;
            float lat0_l = fmaxf(aff_l, 0.0f);
            float v = (lat0_l - acc) /* *STRENGTH=1 */ + aff_l;
            float lv = tanhf(fmaxf(v, 0.0f));
            latf[l] = lv;
            ws[WS_LATFP + (li + 12) * PADW + lj0 + tc + 12] = lv;
        }
    };

    float* buf0 = &s_st[wv][0][0];
    float* buf1 = &s_st[wv][1][0];
    __builtin_amdgcn_sched_barrier(0);
    stage(0, buf0);
    stage(1, buf1);
    VMCNT(3);                 // stage0 done; stage1 in flight
    consume(0, buf0, acc_ht[0], ra[0], ad[0]);
    stage(2, buf0);
    VMCNT(5);                 // stage1 done; stores0(2)+stage2(3) in flight
    consume(1, buf1, acc_ht[1], ra[1], ad[1]);
    stage(3, buf1);
    VMCNT(5);
    consume(2, buf0, acc_ht[2], ra[2], ad[2]);
    VMCNT(2);                 // stage3 done; stores2(2) in flight
    consume(3, buf1, acc_ht[3], ra[3], ad[3]);

    __syncthreads();          // s_st free for reuse
    tiles_epilogue(x, tiles, ws, &s_st[0][0][0], &s_st[1][0][0],
                   0, li, lj0, tc0, lane, tid);
}

// ---------------------------------------------------------------------------
// Kernel 3: corr partials (round-7 pipeline on padded latf) + c=1 tiles
// epilogue.
// ---------------------------------------------------------------------------
__global__ __launch_bounds__(256) void k_corr(const float* __restrict__ latf,
                                              const float* __restrict__ lw,
                                              const float* __restrict__ x,
                                              float* __restrict__ tiles,
                                              float* __restrict__ ws) {
    __shared__ float s_le[640];
    __shared__ float s_g[25][40];
    __shared__ float s_st[4][2][640];
    __shared__ float s_red[4];
    const int tid = threadIdx.x, lane = tid & 63, wv = tid >> 6;
    const int blk = blockIdx.x;
    const int li = blk >> 3;
    const int lj0 = (blk & 7) << 4;

    for (int i = tid; i < 625; i += 256) s_le[i] = ws[WS_LRI + i];
    for (int i = tid; i < 1000; i += 256) {
        int ki = i / 40;
        int col = i - ki * 40;
        s_g[ki][col] = ws[WS_LATFP + (li + ki) * PADW + lj0 + col];
    }
    __syncthreads();

    const int tc0 = wv << 2;
    const int l0 = li * 128 + lj0 + tc0;

    float acc_ht[4], lf[4];
#define HT(n) { \
        const int l = l0 + (n); const long B = (long)l * PATCH; \
        const int peel = (4 - (l & 3)) & 3; \
        const int fmax4 = (PATCH - peel) & ~3; \
        const int tcnt = (PATCH - peel) & 3; \
        float a = 0.0f; \
        if (lane < peel) { \
            int f = lane; int ki = div25(f); int kj = f - 25 * ki; \
            a += s_g[ki][kj + tc0 + (n)] * s_le[f] * fmaxf(lw[B + f], 0.0f); \
        } \
        if (lane < tcnt) { \
            int f = peel + fmax4 + lane; int ki = div25(f); int kj = f - 25 * ki; \
            a += s_g[ki][kj + tc0 + (n)] * s_le[f] * fmaxf(lw[B + f], 0.0f); \
        } \
        if (!lane) lf[n] = latf[l]; \
        acc_ht[n] = a; }
    HT(0) HT(1) HT(2) HT(3)
#undef HT

    auto stage = [&](int n, float* buf) {
        const int l = l0 + n;
        const long B = (long)l * PATCH;
        const int peel = (4 - (l & 3)) & 3;
        const int rem = ((PATCH - peel) >> 2) - 128;
        const float* gp = lw + B + peel + 4 * lane;
        gld16(gp,       buf);
        gld16(gp + 256, buf + 256);
        if (lane < rem) gld16(gp + 512, buf + 512);
    };
    float wsum = 0.0f;
    auto consume = [&](int n, const float* buf, float accin, float lfv) {
        const int l = l0 + n;
        const int peel = (4 - (l & 3)) & 3;
        const int fmax4 = (PATCH - peel) & ~3;
        const int tc = tc0 + n;
        float acc = accin;
#pragma unroll
        for (int j = 0; j < 10; ++j) {
            int fh = j * 64 + lane;
            if (j < 9 || fh < fmax4) {
                float wval = buf[fh];
                int f = peel + fh;
                int ki = div25(f);
                int kj = f - 25 * ki;
                acc += s_g[ki][kj + tc] * s_le[f] * fmaxf(wval, 0.0f);
            }
        }
        for (int o = 32; o; o >>= 1) acc += __shfl_down(acc, o);
        if (!lane) wsum += acc * lfv;
    };

    float* buf0 = &s_st[wv][0][0];
    float* buf1 = &s_st[wv][1][0];
    __builtin_amdgcn_sched_barrier(0);
    stage(0, buf0);
    stage(1, buf1);
    VMCNT(3);
    consume(0, buf0, acc_ht[0], lf[0]);
    stage(2, buf0);
    VMCNT(3);
    consume(1, buf1, acc_ht[1], lf[1]);
    stage(3, buf1);
    VMCNT(3);
    consume(2, buf0, acc_ht[2], lf[2]);
    VMCNT(0);
    consume(3, buf1, acc_ht[3], lf[3]);

    if (!lane) s_red[wv] = wsum;
    __syncthreads();
    if (!tid)
        ws[WS_PART + blk] = s_red[0] + s_red[1] + s_red[2] + s_red[3];

    __syncthreads();          // s_st free for reuse
    tiles_epilogue(x, tiles, ws, &s_st[0][0][0], &s_st[1][0][0],
                   1, li, lj0, tc0, lane, tid);
}

// ---------------------------------------------------------------------------
// Kernel 4: deterministic sum of 1024 partials -> corr scalar.
// ---------------------------------------------------------------------------
__global__ __launch_bounds__(256) void k_reduce(const float* __restrict__ ws,
                                                float* __restrict__ corr) {
    __shared__ float s_red[4];
    const int tid = threadIdx.x;
    const int lane = tid & 63, wv = tid >> 6;
    float acc = 0.0f;
    for (int i = tid; i < NPART; i += 256) acc += ws[WS_PART + i];
    for (int o = 32; o; o >>= 1) acc += __shfl_down(acc, o);
    if (!lane) s_red[wv] = acc;
    __syncthreads();
    if (!tid) corr[0] = s_red[0] + s_red[1] + s_red[2] + s_red[3];
}

// ---------------------------------------------------------------------------
// d_out layout (flat, return order):
//   [0, 16384)              raw_aff   [1,1,128,128]
//   [16384, 32768)          lat       [1,1,128,128]
//   [32768]                 lat_correlations (scalar)
//   [32769, 32769+20480000) tiles     [16384, 1, 1250]
// ---------------------------------------------------------------------------
extern "C" void kernel_launch(void* const* d_in, const int* in_sizes, int n_in,
                              void* d_out, int out_size, void* d_ws, size_t ws_size,
                              hipStream_t stream) {
    const float* x   = (const float*)d_in[0];   // [1,2,152,152]
    const float* rfs = (const float*)d_in[1];   // [16384,1250,1]
    const float* lw  = (const float*)d_in[2];   // [16384,625,1]
    const float* ada = (const float*)d_in[3];   // [1,1,128,128]

    float* out      = (float*)d_out;
    float* raw_aff  = out;
    float* latf     = out + S * S;
    float* corr     = out + 2 * S * S;
    float* tiles    = out + 2 * S * S + 1;
    float* ws       = (float*)d_ws;

    k_init<<<16, 256, 0, stream>>>(ws);
    k_aff<<<4096, 256, 0, stream>>>(x, rfs, ada, raw_aff, ws);
    k_lat<<<1024, 256, 0, stream>>>(raw_aff, ada, lw, x, latf, tiles, ws);
    k_corr<<<1024, 256, 0, stream>>>(latf, lw, x, tiles, ws);
    k_reduce<<<1, 256, 0, stream>>>(ws, corr);
}